// Round 1
// baseline (713.936 us; speedup 1.0000x reference)
//
#include <hip/hip_runtime.h>

#define N_NODES 100000
#define N_EDGES 3200000
#define D_IN    512
#define D_HID   16
#define N_CLS   7

// ---------------- zero fill (agg1) ----------------
__global__ __launch_bounds__(256) void zero_f4(float4* __restrict__ p, int n4) {
    int i = blockIdx.x * 256 + threadIdx.x;
    if (i < n4) p[i] = make_float4(0.f, 0.f, 0.f, 0.f);
}

// ---------------- h1 = x @ W1  (100000x512 @ 512x16) ----------------
// Block = 256 threads = 64 rows x 4 col-quads. W1 staged in LDS as float4.
// Thread (row, jq) computes columns 4*jq .. 4*jq+3 (full k-sum, no reduce).
__global__ __launch_bounds__(256) void gemm1(const float* __restrict__ x,
                                             const float* __restrict__ W1,
                                             float* __restrict__ h1) {
    __shared__ float4 w4s[D_IN * 4];          // 512 rows x 4 quads = 32 KB
    const float4* W1f4 = (const float4*)W1;   // row-major [512][16] -> [2048] float4
    int t = threadIdx.x;
#pragma unroll
    for (int i = 0; i < 8; ++i) w4s[i * 256 + t] = W1f4[i * 256 + t];
    __syncthreads();

    int jq  = t & 3;
    int r   = t >> 2;
    int row = blockIdx.x * 64 + r;
    if (row >= N_NODES) return;

    const float4* xr = (const float4*)(x + (size_t)row * D_IN);
    float4 acc = make_float4(0.f, 0.f, 0.f, 0.f);

#pragma unroll 4
    for (int k4 = 0; k4 < D_IN / 4; ++k4) {
        float4 xv = xr[k4];
        float4 w0 = w4s[(k4 * 4 + 0) * 4 + jq];
        float4 w1 = w4s[(k4 * 4 + 1) * 4 + jq];
        float4 w2 = w4s[(k4 * 4 + 2) * 4 + jq];
        float4 w3 = w4s[(k4 * 4 + 3) * 4 + jq];
        acc.x = fmaf(xv.x, w0.x, acc.x); acc.y = fmaf(xv.x, w0.y, acc.y);
        acc.z = fmaf(xv.x, w0.z, acc.z); acc.w = fmaf(xv.x, w0.w, acc.w);
        acc.x = fmaf(xv.y, w1.x, acc.x); acc.y = fmaf(xv.y, w1.y, acc.y);
        acc.z = fmaf(xv.y, w1.z, acc.z); acc.w = fmaf(xv.y, w1.w, acc.w);
        acc.x = fmaf(xv.z, w2.x, acc.x); acc.y = fmaf(xv.z, w2.y, acc.y);
        acc.z = fmaf(xv.z, w2.z, acc.z); acc.w = fmaf(xv.z, w2.w, acc.w);
        acc.x = fmaf(xv.w, w3.x, acc.x); acc.y = fmaf(xv.w, w3.y, acc.y);
        acc.z = fmaf(xv.w, w3.z, acc.z); acc.w = fmaf(xv.w, w3.w, acc.w);
    }
    ((float4*)(h1 + (size_t)row * D_HID))[jq] = acc;
}

// ---------------- agg1[dst] += h1[src]  (edge-parallel, thread = (edge, j)) ----
__global__ __launch_bounds__(256) void scatter1(const int* __restrict__ src,
                                                const int* __restrict__ dst,
                                                const float* __restrict__ h1,
                                                float* __restrict__ agg) {
    int tid = blockIdx.x * 256 + threadIdx.x;   // 51.2M threads
    int e = tid >> 4;
    int j = tid & 15;
    if (e >= N_EDGES) return;
    int s = src[e];
    int d = dst[e];
    atomicAdd(&agg[(size_t)d * D_HID + j], h1[(size_t)s * D_HID + j]);
}

// ---------------- h2 = relu(agg1 + b1) @ W2  (100000x16 @ 16x7) ----------------
__global__ __launch_bounds__(256) void layer2(const float* __restrict__ agg,
                                              const float* __restrict__ b1,
                                              const float* __restrict__ W2,
                                              float* __restrict__ h2) {
    __shared__ float w2s[D_HID * N_CLS];
    __shared__ float b1s[D_HID];
    int t = threadIdx.x;
    if (t < D_HID * N_CLS) w2s[t] = W2[t];
    if (t < D_HID) b1s[t] = b1[t];
    __syncthreads();

    int n = blockIdx.x * 256 + t;
    if (n >= N_NODES) return;

    const float4* a4 = (const float4*)(agg + (size_t)n * D_HID);
    float rel[D_HID];
#pragma unroll
    for (int q = 0; q < 4; ++q) {
        float4 v = a4[q];
        rel[4 * q + 0] = fmaxf(v.x + b1s[4 * q + 0], 0.f);
        rel[4 * q + 1] = fmaxf(v.y + b1s[4 * q + 1], 0.f);
        rel[4 * q + 2] = fmaxf(v.z + b1s[4 * q + 2], 0.f);
        rel[4 * q + 3] = fmaxf(v.w + b1s[4 * q + 3], 0.f);
    }
    float o[N_CLS];
#pragma unroll
    for (int c = 0; c < N_CLS; ++c) o[c] = 0.f;
#pragma unroll
    for (int j = 0; j < D_HID; ++j) {
#pragma unroll
        for (int c = 0; c < N_CLS; ++c)
            o[c] = fmaf(rel[j], w2s[j * N_CLS + c], o[c]);
    }
    float* hp = h2 + (size_t)n * N_CLS;
#pragma unroll
    for (int c = 0; c < N_CLS; ++c) hp[c] = o[c];
}

// ---------------- out[i] = b2[i % 7] ----------------
__global__ __launch_bounds__(256) void out_init(const float* __restrict__ b2,
                                                float* __restrict__ out) {
    int i = blockIdx.x * 256 + threadIdx.x;
    if (i >= N_NODES * N_CLS) return;
    int c = i - (i / N_CLS) * N_CLS;
    out[i] = b2[c];
}

// ---------------- out[dst] += h2[src]  (thread = (edge, c)) ----------------
__global__ __launch_bounds__(256) void scatter2(const int* __restrict__ src,
                                                const int* __restrict__ dst,
                                                const float* __restrict__ h2,
                                                float* __restrict__ out) {
    int tid = blockIdx.x * 256 + threadIdx.x;   // 22.4M threads
    if (tid >= N_EDGES * N_CLS) return;
    int e = tid / N_CLS;
    int c = tid - e * N_CLS;
    int s = src[e];
    int d = dst[e];
    atomicAdd(&out[(size_t)d * N_CLS + c], h2[(size_t)s * N_CLS + c]);
}

extern "C" void kernel_launch(void* const* d_in, const int* in_sizes, int n_in,
                              void* d_out, int out_size, void* d_ws, size_t ws_size,
                              hipStream_t stream) {
    const float* x  = (const float*)d_in[0];
    const int*   ei = (const int*)d_in[1];
    const float* W1 = (const float*)d_in[2];
    const float* b1 = (const float*)d_in[3];
    const float* W2 = (const float*)d_in[4];
    const float* b2 = (const float*)d_in[5];
    float* out = (float*)d_out;

    char* ws = (char*)d_ws;
    float* h1   = (float*)(ws);                 // 100000*16*4 = 6.4 MB
    float* agg1 = (float*)(ws + 6400000);       // 6.4 MB
    float* h2   = (float*)(ws + 12800000);      // 100000*7*4 = 2.8 MB

    const int* src = ei;             // edge_index[0]
    const int* dst = ei + N_EDGES;   // edge_index[1]

    // zero agg1 (1.6M floats = 400000 float4)
    zero_f4<<<(400000 + 255) / 256, 256, 0, stream>>>((float4*)agg1, 400000);

    // h1 = x @ W1
    gemm1<<<(N_NODES + 63) / 64, 256, 0, stream>>>(x, W1, h1);

    // agg1[dst] += h1[src]
    scatter1<<<(N_EDGES * 16) / 256, 256, 0, stream>>>(src, dst, h1, agg1);

    // h2 = relu(agg1 + b1) @ W2
    layer2<<<(N_NODES + 255) / 256, 256, 0, stream>>>(agg1, b1, W2, h2);

    // out = b2 broadcast
    out_init<<<(N_NODES * N_CLS + 255) / 256, 256, 0, stream>>>(b2, out);

    // out[dst] += h2[src]
    scatter2<<<(N_EDGES * N_CLS + 255) / 256, 256, 0, stream>>>(src, dst, h2, out);
}